// Round 17
// baseline (3246.988 us; speedup 1.0000x reference)
//
#include <hip/hip_runtime.h>
#include <cstdint>
#include <cstddef>

static constexpr int TT = 1024;   // time steps
static constexpr int BB = 32;     // batch
static constexpr int CC = 256;    // channels (= 2H)
static constexpr int HH = 128;    // hidden per direction
static constexpr int GG = 512;    // 4H gates
static constexpr int MM = TT * BB;

typedef float f32x4v __attribute__((ext_vector_type(4)));
typedef short bf16x8 __attribute__((ext_vector_type(8)));

__device__ __forceinline__ float fsig(float x) { return 1.f / (1.f + __expf(-x)); }
__device__ __forceinline__ float ftanh(float x) {
  float e = __expf(2.f * x);
  return 1.f - 2.f / (e + 1.f);
}
__device__ __forceinline__ ushort bf16_rn(float x) {
  union { float f; uint u; } v; v.f = x;
  const uint r = v.u + 0x7fffu + ((v.u >> 16) & 1u);
  return (ushort)(r >> 16);
}
__device__ __forceinline__ float bf16_to_f(ushort h) {
  union { uint u; float f; } v; v.u = ((uint)h) << 16;
  return v.f;
}
__device__ __forceinline__ uint pack2(ushort a, ushort b) { return (uint)a | ((uint)b << 16); }

// ---------------- x[B][C][T] -> Xhi/Xlo[T*B][C] (bf16 hi/lo split) ----------------
__global__ __launch_bounds__(256) void k_transpose_cvt_in(const float* __restrict__ x,
                                                          ushort* __restrict__ xhi,
                                                          ushort* __restrict__ xlo) {
  __shared__ float tile[32][33];
  const int t0 = blockIdx.x * 32, c0 = blockIdx.y * 32, b = blockIdx.z;
  const int tx = threadIdx.x, ty = threadIdx.y;
#pragma unroll
  for (int i = 0; i < 4; i++) {
    const int cc = ty + i * 8;
    tile[cc][tx] = x[((size_t)b * CC + (c0 + cc)) * TT + t0 + tx];
  }
  __syncthreads();
#pragma unroll
  for (int i = 0; i < 4; i++) {
    const int tt = ty + i * 8;
    const float v = tile[tx][tt];
    const ushort hi = bf16_rn(v);
    const size_t idx = ((size_t)(t0 + tt) * BB + b) * CC + c0 + tx;
    xhi[idx] = hi;
    xlo[idx] = bf16_rn(v - bf16_to_f(hi));
  }
}

// ---------------- h2[T][B][C] -> out[B][C][T] ----------------
__global__ __launch_bounds__(256) void k_transpose_out(const float* __restrict__ h2,
                                                       float* __restrict__ out) {
  __shared__ float tile[32][33];
  const int t0 = blockIdx.x * 32, c0 = blockIdx.y * 32, b = blockIdx.z;
  const int tx = threadIdx.x, ty = threadIdx.y;
#pragma unroll
  for (int i = 0; i < 4; i++) {
    const int tt = ty + i * 8;
    tile[tt][tx] = h2[((size_t)(t0 + tt) * BB + b) * CC + c0 + tx];
  }
  __syncthreads();
#pragma unroll
  for (int i = 0; i < 4; i++) {
    const int cc = ty + i * 8;
    out[((size_t)b * CC + (c0 + cc)) * TT + t0 + tx] = tile[tx][cc];
  }
}

// ---------------- MFMA GEMM: gx[d][m][g] = A[m][:]·W[d][g][:] + bias ----------------
// Verified R10/R14/R15: absmax 9.77e-4, ~50us each.
__global__ __launch_bounds__(256) void k_gemm_mfma(const ushort* __restrict__ Ahi,
                                                   const ushort* __restrict__ Alo,
                                                   const float* __restrict__ W,
                                                   const float* __restrict__ bih,
                                                   const float* __restrict__ bhh,
                                                   float* __restrict__ gx) {
  const int d = blockIdx.z;
  const int g0 = blockIdx.x * 64;
  const int m0 = blockIdx.y * 128;
  const float* Wd = W + (size_t)d * GG * CC;

  __shared__ ushort Ah[128][64];
  __shared__ ushort Al[128][64];
  __shared__ ushort Bh[64][64];
  __shared__ ushort Bl[64][64];

  const int tid = threadIdx.x;
  const int lane = tid & 63;
  const int wid = tid >> 6;
  const int wm = (wid >> 1) * 64;
  const int wg = (wid & 1) * 32;

  f32x4v acc[4][2] = {};

  for (int k0 = 0; k0 < CC; k0 += 64) {
    __syncthreads();
#pragma unroll
    for (int c = 0; c < 4; c++) {
      const int f8 = c * 256 + tid;
      const int r = f8 >> 3;
      const int kb = f8 & 7;
      const int sw = (kb ^ (r & 7)) << 3;
      const uint4 vh = *(const uint4*)&Ahi[(size_t)(m0 + r) * CC + k0 + kb * 8];
      const uint4 vl = *(const uint4*)&Alo[(size_t)(m0 + r) * CC + k0 + kb * 8];
      *(uint4*)&Ah[r][sw] = vh;
      *(uint4*)&Al[r][sw] = vl;
    }
#pragma unroll
    for (int c = 0; c < 4; c++) {
      const int f4 = c * 256 + tid;
      const int g = f4 >> 4;
      const int k4 = f4 & 15;
      const float4 wv = *(const float4*)&Wd[(size_t)(g0 + g) * CC + k0 + k4 * 4];
      ushort h0 = bf16_rn(wv.x), h1 = bf16_rn(wv.y), h2 = bf16_rn(wv.z), h3 = bf16_rn(wv.w);
      ushort l0 = bf16_rn(wv.x - bf16_to_f(h0)), l1 = bf16_rn(wv.y - bf16_to_f(h1));
      ushort l2 = bf16_rn(wv.z - bf16_to_f(h2)), l3 = bf16_rn(wv.w - bf16_to_f(h3));
      const int off = (((k4 >> 1) ^ (g & 7)) << 3) | ((k4 & 1) * 4);
      uint2 ph; ph.x = pack2(h0, h1); ph.y = pack2(h2, h3);
      uint2 pl; pl.x = pack2(l0, l1); pl.y = pack2(l2, l3);
      *(uint2*)&Bh[g][off] = ph;
      *(uint2*)&Bl[g][off] = pl;
    }
    __syncthreads();
#pragma unroll
    for (int h = 0; h < 2; h++) {
      const int kb = h * 4 + (lane >> 4);
      bf16x8 afh[4], afl[4], bfh[2], bfl[2];
#pragma unroll
      for (int i = 0; i < 4; i++) {
        const int row = wm + i * 16 + (lane & 15);
        const int sw = (kb ^ (row & 7)) << 3;
        afh[i] = *(const bf16x8*)&Ah[row][sw];
        afl[i] = *(const bf16x8*)&Al[row][sw];
      }
#pragma unroll
      for (int j = 0; j < 2; j++) {
        const int gr = wg + j * 16 + (lane & 15);
        const int sw = (kb ^ (gr & 7)) << 3;
        bfh[j] = *(const bf16x8*)&Bh[gr][sw];
        bfl[j] = *(const bf16x8*)&Bl[gr][sw];
      }
#pragma unroll
      for (int i = 0; i < 4; i++)
#pragma unroll
        for (int j = 0; j < 2; j++) {
          acc[i][j] = __builtin_amdgcn_mfma_f32_16x16x32_bf16(afh[i], bfh[j], acc[i][j], 0, 0, 0);
          acc[i][j] = __builtin_amdgcn_mfma_f32_16x16x32_bf16(afh[i], bfl[j], acc[i][j], 0, 0, 0);
          acc[i][j] = __builtin_amdgcn_mfma_f32_16x16x32_bf16(afl[i], bfh[j], acc[i][j], 0, 0, 0);
        }
    }
  }
  const int col = lane & 15;
  const int rbase = (lane >> 4) * 4;
#pragma unroll
  for (int j = 0; j < 2; j++) {
    const int g = g0 + wg + j * 16 + col;
    const float bias = bih[d * GG + g] + bhh[d * GG + g];
#pragma unroll
    for (int i = 0; i < 4; i++) {
      const int mrow = m0 + wm + i * 16 + rbase;
#pragma unroll
      for (int rr = 0; rr < 4; rr++)
        gx[((size_t)d * MM + mrow + rr) * GG + g] = acc[i][j][rr] + bias;
    }
  }
}

// dot for one sequence: hsrc = &h_s[seq][q*32], pdst = &part[seq][q][j][0]
__device__ __forceinline__ void rec_dot4(const float* __restrict__ hsrc,
                                         float* __restrict__ pdst,
                                         const float4 (&w4)[4][8]) {
  const float4* hq = (const float4*)hsrc;
  float a0 = 0.f, a1 = 0.f, a2 = 0.f, a3 = 0.f;
#pragma unroll
  for (int k = 0; k < 8; k++) {
    const float4 hv = hq[k];
    a0 = fmaf(w4[0][k].x, hv.x, a0); a0 = fmaf(w4[0][k].y, hv.y, a0);
    a0 = fmaf(w4[0][k].z, hv.z, a0); a0 = fmaf(w4[0][k].w, hv.w, a0);
    a1 = fmaf(w4[1][k].x, hv.x, a1); a1 = fmaf(w4[1][k].y, hv.y, a1);
    a1 = fmaf(w4[1][k].z, hv.z, a1); a1 = fmaf(w4[1][k].w, hv.w, a1);
    a2 = fmaf(w4[2][k].x, hv.x, a2); a2 = fmaf(w4[2][k].y, hv.y, a2);
    a2 = fmaf(w4[2][k].z, hv.z, a2); a2 = fmaf(w4[2][k].w, hv.w, a2);
    a3 = fmaf(w4[3][k].x, hv.x, a3); a3 = fmaf(w4[3][k].y, hv.y, a3);
    a3 = fmaf(w4[3][k].z, hv.z, a3); a3 = fmaf(w4[3][k].w, hv.w, a3);
  }
  *(float4*)pdst = make_float4(a0, a1, a2, a3);
}

// ---------------- paired-batch recurrence: one WG per (d, batch-pair) ----------------
// KEY: pair two sequences of the SAME direction -> they share W_hh, so per-thread
// weights stay at R5's 128 floats (R10/R11's fwd+bwd pairing doubled weights ->
// scratch spill). Phase X: {dot_B || act_A}, phase Y: {dot_A(s+1) || act_B}.
// The ~1200cyc/step serial act chain (part-read latency + sigma/tanh chain +
// h-write: proven irreducible intra-sequence by R8/R9/R16 nulls) now hides under
// the OTHER sequence's 512cyc dot issue; barriers drop to 1 per sequence-step.
// 32 WGs (2d x 16 pairs); each thread does both dots (256 FMA/iter, advancing
// both sequences 1 step).
__global__ __launch_bounds__(512, 1) void k_lstm_rec_pair(const float* __restrict__ gx,
                                                          const float* __restrict__ Whh,
                                                          float* __restrict__ hf32,
                                                          ushort* __restrict__ hhi,
                                                          ushort* __restrict__ hlo,
                                                          int store_bf16) {
  const int pair = blockIdx.x & 15;
  const int d = blockIdx.x >> 4;
  const int b0 = pair * 2, b1 = pair * 2 + 1;
  const int tid = threadIdx.x;
  const int q = tid >> 7;       // K-quarter (wave-uniform)
  const int j = tid & 127;
  __shared__ __align__(16) float h_s[2][HH];
  __shared__ __align__(16) float part[2][4][HH][4];  // [seq][q][j][gate]

  float4 w4[4][8];  // shared by both sequences (same d)
  {
    const float* base = Whh + (size_t)d * GG * HH;
#pragma unroll
    for (int gi = 0; gi < 4; gi++) {
      const float4* wrow = (const float4*)(base + (size_t)(gi * HH + j) * HH + q * 32);
#pragma unroll
      for (int k = 0; k < 8; k++) w4[gi][k] = wrow[k];
    }
  }
#pragma unroll
  for (int gi = 0; gi < 4; gi++)
#pragma unroll
    for (int k = 0; k < 8; k++)
      asm volatile("" : "+v"(w4[gi][k].x), "+v"(w4[gi][k].y), "+v"(w4[gi][k].z), "+v"(w4[gi][k].w));

  if (tid < HH) { h_s[0][tid] = 0.f; h_s[1][tid] = 0.f; }
  float cA = 0.f, cB = 0.f;

  const float* gxA = gx + ((size_t)d * TT * BB + b0) * (size_t)GG;
  const float* gxB = gx + ((size_t)d * TT * BB + b1) * (size_t)GG;
  const size_t stride = (size_t)BB * GG;
  int t = d ? (TT - 1) : 0;
  const int tdir = d ? -1 : 1;
  const bool is_act = (tid < HH);

  float gA0 = 0.f, gA1 = 0.f, gA2 = 0.f, gA3 = 0.f;
  float gB0 = 0.f, gB1 = 0.f, gB2 = 0.f, gB3 = 0.f;
  if (is_act) {
    const float* a = gxA + (size_t)t * stride + j;
    gA0 = a[0]; gA1 = a[HH]; gA2 = a[2 * HH]; gA3 = a[3 * HH];
    const float* bq = gxB + (size_t)t * stride + j;
    gB0 = bq[0]; gB1 = bq[HH]; gB2 = bq[2 * HH]; gB3 = bq[3 * HH];
  }
  __syncthreads();

  // prologue: dot_A(step 0) with h_A = 0
  rec_dot4(&h_s[0][q * 32], &part[0][q][j][0], w4);
  __syncthreads();

  for (int s = 0; s < TT; s++) {
    // ---------- Phase X: dot_B(s) || act_A(s) ----------
    float gAn0 = 0.f, gAn1 = 0.f, gAn2 = 0.f, gAn3 = 0.f;
    rec_dot4(&h_s[1][q * 32], &part[1][q][j][0], w4);
    if (is_act) {
      if (s + 1 < TT) {  // prefetch A's next gx; retires under phase Y's dot
        const float* a = gxA + (size_t)(t + tdir) * stride + j;
        gAn0 = a[0]; gAn1 = a[HH]; gAn2 = a[2 * HH]; gAn3 = a[3 * HH];
      }
      const float4 p0 = *(const float4*)&part[0][0][j][0];
      const float4 p1 = *(const float4*)&part[0][1][j][0];
      const float4 p2 = *(const float4*)&part[0][2][j][0];
      const float4 p3 = *(const float4*)&part[0][3][j][0];
      const float i_g = fsig(p0.x + p1.x + p2.x + p3.x + gA0);
      const float f_g = fsig(p0.y + p1.y + p2.y + p3.y + gA1);
      const float g_g = ftanh(p0.z + p1.z + p2.z + p3.z + gA2);
      const float o_g = fsig(p0.w + p1.w + p2.w + p3.w + gA3);
      cA = f_g * cA + i_g * g_g;
      const float h = o_g * ftanh(cA);
      h_s[0][j] = h;
      const size_t idx = ((size_t)t * BB + b0) * CC + d * HH + j;
      if (store_bf16) {
        const ushort hi = bf16_rn(h);
        hhi[idx] = hi;
        hlo[idx] = bf16_rn(h - bf16_to_f(hi));
      } else {
        hf32[idx] = h;
      }
    }
    __syncthreads();

    // ---------- Phase Y: dot_A(s+1) || act_B(s) ----------
    float gBn0 = 0.f, gBn1 = 0.f, gBn2 = 0.f, gBn3 = 0.f;
    if (s + 1 < TT) rec_dot4(&h_s[0][q * 32], &part[0][q][j][0], w4);
    if (is_act) {
      if (s + 1 < TT) {
        const float* bq = gxB + (size_t)(t + tdir) * stride + j;
        gBn0 = bq[0]; gBn1 = bq[HH]; gBn2 = bq[2 * HH]; gBn3 = bq[3 * HH];
      }
      const float4 p0 = *(const float4*)&part[1][0][j][0];
      const float4 p1 = *(const float4*)&part[1][1][j][0];
      const float4 p2 = *(const float4*)&part[1][2][j][0];
      const float4 p3 = *(const float4*)&part[1][3][j][0];
      const float i_g = fsig(p0.x + p1.x + p2.x + p3.x + gB0);
      const float f_g = fsig(p0.y + p1.y + p2.y + p3.y + gB1);
      const float g_g = ftanh(p0.z + p1.z + p2.z + p3.z + gB2);
      const float o_g = fsig(p0.w + p1.w + p2.w + p3.w + gB3);
      cB = f_g * cB + i_g * g_g;
      const float h = o_g * ftanh(cB);
      h_s[1][j] = h;
      const size_t idx = ((size_t)t * BB + b1) * CC + d * HH + j;
      if (store_bf16) {
        const ushort hi = bf16_rn(h);
        hhi[idx] = hi;
        hlo[idx] = bf16_rn(h - bf16_to_f(hi));
      } else {
        hf32[idx] = h;
      }
    }
    __syncthreads();

    gA0 = gAn0; gA1 = gAn1; gA2 = gAn2; gA3 = gAn3;
    gB0 = gBn0; gB1 = gBn1; gB2 = gBn2; gB3 = gBn3;
    t += tdir;
  }
}

extern "C" void kernel_launch(void* const* d_in, const int* in_sizes, int n_in,
                              void* d_out, int out_size, void* d_ws, size_t ws_size,
                              hipStream_t stream) {
  const float* x    = (const float*)d_in[0];
  const float* W_ih = (const float*)d_in[1];  // [2][2][512][256]
  const float* W_hh = (const float*)d_in[2];  // [2][2][512][128]
  const float* b_ih = (const float*)d_in[3];  // [2][2][512]
  const float* b_hh = (const float*)d_in[4];
  float* out = (float*)d_out;

  if (ws_size < (size_t)160 * 1024 * 1024) return;

  // A-region (32 MiB) recycled: Xhi/Xlo -> h1hi/h1lo -> h2 fp32
  char* ws = (char*)d_ws;
  ushort* abf_hi = (ushort*)ws;                              // 16 MiB
  ushort* abf_lo = (ushort*)(ws + (size_t)16 * 1024 * 1024); // 16 MiB
  float*  h2     = (float*)ws;                               // 32 MiB (rec1 output)
  float*  gxbuf  = (float*)(ws + (size_t)32 * 1024 * 1024);  // [D][M][512] 128 MiB

  const dim3 tb(32, 8);
  const dim3 tg(TT / 32, CC / 32, BB);
  const dim3 gemm_grid(GG / 64, MM / 128, 2);

  k_transpose_cvt_in<<<tg, tb, 0, stream>>>(x, abf_hi, abf_lo);
  k_gemm_mfma<<<gemm_grid, 256, 0, stream>>>(abf_hi, abf_lo, W_ih, b_ih, b_hh, gxbuf);
  k_lstm_rec_pair<<<32, 512, 0, stream>>>(gxbuf, W_hh, nullptr, abf_hi, abf_lo, 1);
  k_gemm_mfma<<<gemm_grid, 256, 0, stream>>>(abf_hi, abf_lo, W_ih + 2 * GG * CC,
                                             b_ih + 2 * GG, b_hh + 2 * GG, gxbuf);
  k_lstm_rec_pair<<<32, 512, 0, stream>>>(gxbuf, W_hh + 2 * GG * HH, h2, nullptr, nullptr, 0);
  k_transpose_out<<<tg, tb, 0, stream>>>(h2, out);
}

// Round 18
// 1797.925 us; speedup vs baseline: 1.8060x; 1.8060x over previous
//
#include <hip/hip_runtime.h>
#include <cstdint>
#include <cstddef>

static constexpr int TT = 1024;   // time steps
static constexpr int BB = 32;     // batch
static constexpr int CC = 256;    // channels (= 2H)
static constexpr int HH = 128;    // hidden per direction
static constexpr int GG = 512;    // 4H gates
static constexpr int MM = TT * BB;

typedef float f32x4v __attribute__((ext_vector_type(4)));
typedef short bf16x8 __attribute__((ext_vector_type(8)));

__device__ __forceinline__ float fsig(float x) { return 1.f / (1.f + __expf(-x)); }
__device__ __forceinline__ float ftanh(float x) {
  float e = __expf(2.f * x);
  return 1.f - 2.f / (e + 1.f);
}
__device__ __forceinline__ ushort bf16_rn(float x) {
  union { float f; uint u; } v; v.f = x;
  const uint r = v.u + 0x7fffu + ((v.u >> 16) & 1u);
  return (ushort)(r >> 16);
}
__device__ __forceinline__ float bf16_to_f(ushort h) {
  union { uint u; float f; } v; v.u = ((uint)h) << 16;
  return v.f;
}
__device__ __forceinline__ uint pack2(ushort a, ushort b) { return (uint)a | ((uint)b << 16); }

// ---------------- x[B][C][T] -> Xhi/Xlo[T*B][C] (bf16 hi/lo split) ----------------
__global__ __launch_bounds__(256) void k_transpose_cvt_in(const float* __restrict__ x,
                                                          ushort* __restrict__ xhi,
                                                          ushort* __restrict__ xlo) {
  __shared__ float tile[32][33];
  const int t0 = blockIdx.x * 32, c0 = blockIdx.y * 32, b = blockIdx.z;
  const int tx = threadIdx.x, ty = threadIdx.y;
#pragma unroll
  for (int i = 0; i < 4; i++) {
    const int cc = ty + i * 8;
    tile[cc][tx] = x[((size_t)b * CC + (c0 + cc)) * TT + t0 + tx];
  }
  __syncthreads();
#pragma unroll
  for (int i = 0; i < 4; i++) {
    const int tt = ty + i * 8;
    const float v = tile[tx][tt];
    const ushort hi = bf16_rn(v);
    const size_t idx = ((size_t)(t0 + tt) * BB + b) * CC + c0 + tx;
    xhi[idx] = hi;
    xlo[idx] = bf16_rn(v - bf16_to_f(hi));
  }
}

// ---------------- h2[T][B][C] -> out[B][C][T] ----------------
__global__ __launch_bounds__(256) void k_transpose_out(const float* __restrict__ h2,
                                                       float* __restrict__ out) {
  __shared__ float tile[32][33];
  const int t0 = blockIdx.x * 32, c0 = blockIdx.y * 32, b = blockIdx.z;
  const int tx = threadIdx.x, ty = threadIdx.y;
#pragma unroll
  for (int i = 0; i < 4; i++) {
    const int tt = ty + i * 8;
    tile[tt][tx] = h2[((size_t)(t0 + tt) * BB + b) * CC + c0 + tx];
  }
  __syncthreads();
#pragma unroll
  for (int i = 0; i < 4; i++) {
    const int cc = ty + i * 8;
    out[((size_t)b * CC + (c0 + cc)) * TT + t0 + tx] = tile[tx][cc];
  }
}

// ---------------- MFMA GEMM: gx[d][m][g] = A[m][:]·W[d][g][:] + bias ----------------
// Verified R10/R14/R15: absmax 9.77e-4, ~50us each.
__global__ __launch_bounds__(256) void k_gemm_mfma(const ushort* __restrict__ Ahi,
                                                   const ushort* __restrict__ Alo,
                                                   const float* __restrict__ W,
                                                   const float* __restrict__ bih,
                                                   const float* __restrict__ bhh,
                                                   float* __restrict__ gx) {
  const int d = blockIdx.z;
  const int g0 = blockIdx.x * 64;
  const int m0 = blockIdx.y * 128;
  const float* Wd = W + (size_t)d * GG * CC;

  __shared__ ushort Ah[128][64];
  __shared__ ushort Al[128][64];
  __shared__ ushort Bh[64][64];
  __shared__ ushort Bl[64][64];

  const int tid = threadIdx.x;
  const int lane = tid & 63;
  const int wid = tid >> 6;
  const int wm = (wid >> 1) * 64;
  const int wg = (wid & 1) * 32;

  f32x4v acc[4][2] = {};

  for (int k0 = 0; k0 < CC; k0 += 64) {
    __syncthreads();
#pragma unroll
    for (int c = 0; c < 4; c++) {
      const int f8 = c * 256 + tid;
      const int r = f8 >> 3;
      const int kb = f8 & 7;
      const int sw = (kb ^ (r & 7)) << 3;
      const uint4 vh = *(const uint4*)&Ahi[(size_t)(m0 + r) * CC + k0 + kb * 8];
      const uint4 vl = *(const uint4*)&Alo[(size_t)(m0 + r) * CC + k0 + kb * 8];
      *(uint4*)&Ah[r][sw] = vh;
      *(uint4*)&Al[r][sw] = vl;
    }
#pragma unroll
    for (int c = 0; c < 4; c++) {
      const int f4 = c * 256 + tid;
      const int g = f4 >> 4;
      const int k4 = f4 & 15;
      const float4 wv = *(const float4*)&Wd[(size_t)(g0 + g) * CC + k0 + k4 * 4];
      ushort h0 = bf16_rn(wv.x), h1 = bf16_rn(wv.y), h2 = bf16_rn(wv.z), h3 = bf16_rn(wv.w);
      ushort l0 = bf16_rn(wv.x - bf16_to_f(h0)), l1 = bf16_rn(wv.y - bf16_to_f(h1));
      ushort l2 = bf16_rn(wv.z - bf16_to_f(h2)), l3 = bf16_rn(wv.w - bf16_to_f(h3));
      const int off = (((k4 >> 1) ^ (g & 7)) << 3) | ((k4 & 1) * 4);
      uint2 ph; ph.x = pack2(h0, h1); ph.y = pack2(h2, h3);
      uint2 pl; pl.x = pack2(l0, l1); pl.y = pack2(l2, l3);
      *(uint2*)&Bh[g][off] = ph;
      *(uint2*)&Bl[g][off] = pl;
    }
    __syncthreads();
#pragma unroll
    for (int h = 0; h < 2; h++) {
      const int kb = h * 4 + (lane >> 4);
      bf16x8 afh[4], afl[4], bfh[2], bfl[2];
#pragma unroll
      for (int i = 0; i < 4; i++) {
        const int row = wm + i * 16 + (lane & 15);
        const int sw = (kb ^ (row & 7)) << 3;
        afh[i] = *(const bf16x8*)&Ah[row][sw];
        afl[i] = *(const bf16x8*)&Al[row][sw];
      }
#pragma unroll
      for (int j = 0; j < 2; j++) {
        const int gr = wg + j * 16 + (lane & 15);
        const int sw = (kb ^ (gr & 7)) << 3;
        bfh[j] = *(const bf16x8*)&Bh[gr][sw];
        bfl[j] = *(const bf16x8*)&Bl[gr][sw];
      }
#pragma unroll
      for (int i = 0; i < 4; i++)
#pragma unroll
        for (int j = 0; j < 2; j++) {
          acc[i][j] = __builtin_amdgcn_mfma_f32_16x16x32_bf16(afh[i], bfh[j], acc[i][j], 0, 0, 0);
          acc[i][j] = __builtin_amdgcn_mfma_f32_16x16x32_bf16(afh[i], bfl[j], acc[i][j], 0, 0, 0);
          acc[i][j] = __builtin_amdgcn_mfma_f32_16x16x32_bf16(afl[i], bfh[j], acc[i][j], 0, 0, 0);
        }
    }
  }
  const int col = lane & 15;
  const int rbase = (lane >> 4) * 4;
#pragma unroll
  for (int j = 0; j < 2; j++) {
    const int g = g0 + wg + j * 16 + col;
    const float bias = bih[d * GG + g] + bhh[d * GG + g];
#pragma unroll
    for (int i = 0; i < 4; i++) {
      const int mrow = m0 + wm + i * 16 + rbase;
#pragma unroll
      for (int rr = 0; rr < 4; rr++)
        gx[((size_t)d * MM + mrow + rr) * GG + g] = acc[i][j][rr] + bias;
    }
  }
}

// ---------------- persistent recurrence: one WG per (d,b) — R15 EXACT (session best) --
// Best measured rec across 11 structural variants (R5/R15: 798-822us). Thread
// (q=tid>>7, j=tid&127): 4 gates x 32-K quarter, float4 weights register-resident.
// 8 uniform b128 h-reads/thread, part[] LDS reduction, 2-wave act, plain
// __syncthreads. Falsified alternatives: lgkm-only barriers (R8 +2%), deferred
// store (R16 +4%), quad-shfl reduce (R12 +34%), act-spread (R9 +24%), paired-batch
// (R17 +88%), fwd+bwd pair (R11 spill), MFMA rec (R14 +155%). Latency-bound:
// per-step serial chain ~1930cyc (h-read + dot + part round-trip + act chain +
// 2 barriers); weights = half the register file -> 1 sequence/CU structural.
__global__ __launch_bounds__(512, 1) void k_lstm_rec(const float* __restrict__ gx,
                                                     const float* __restrict__ Whh,
                                                     float* __restrict__ hf32,
                                                     ushort* __restrict__ hhi,
                                                     ushort* __restrict__ hlo,
                                                     int store_bf16) {
  const int b = blockIdx.x & 31;
  const int d = blockIdx.x >> 5;
  const int tid = threadIdx.x;
  const int q = tid >> 7;       // K-quarter (wave-uniform)
  const int j = tid & 127;
  __shared__ __align__(16) float h_s[HH];
  __shared__ __align__(16) float part[4][HH][4];

  float4 w4[4][8];
  {
    const float* base = Whh + (size_t)d * GG * HH;
#pragma unroll
    for (int gi = 0; gi < 4; gi++) {
      const float4* wrow = (const float4*)(base + (size_t)(gi * HH + j) * HH + q * 32);
#pragma unroll
      for (int k = 0; k < 8; k++) w4[gi][k] = wrow[k];
    }
  }
#pragma unroll
  for (int gi = 0; gi < 4; gi++)
#pragma unroll
    for (int k = 0; k < 8; k++)
      asm volatile("" : "+v"(w4[gi][k].x), "+v"(w4[gi][k].y), "+v"(w4[gi][k].z), "+v"(w4[gi][k].w));

  if (tid < HH) h_s[tid] = 0.f;
  float c = 0.f;

  const float* gxb = gx + ((size_t)d * TT * BB + b) * (size_t)GG;
  const size_t stride = (size_t)BB * GG;
  int t = d ? (TT - 1) : 0;
  const int tdir = d ? -1 : 1;
  const bool is_act = (tid < HH);

  float gxc0 = 0.f, gxc1 = 0.f, gxc2 = 0.f, gxc3 = 0.f;
  if (is_act) {
    const float* g0 = gxb + (size_t)t * stride + j;
    gxc0 = g0[0]; gxc1 = g0[HH]; gxc2 = g0[2 * HH]; gxc3 = g0[3 * HH];
  }
  __syncthreads();

  for (int s = 0; s < TT; s++) {
    // prefetch next step's gx (independent of h)
    float gxn0 = 0.f, gxn1 = 0.f, gxn2 = 0.f, gxn3 = 0.f;
    if (is_act && s + 1 < TT) {
      const float* g0 = gxb + (size_t)(t + tdir) * stride + j;
      gxn0 = g0[0]; gxn1 = g0[HH]; gxn2 = g0[2 * HH]; gxn3 = g0[3 * HH];
    }

    // h K-slice: 8 uniform b128 reads
    const float4* hq = (const float4*)(h_s + q * 32);
    float a0 = 0.f, a1 = 0.f, a2 = 0.f, a3 = 0.f;
#pragma unroll
    for (int k = 0; k < 8; k++) {
      const float4 hv = hq[k];
      a0 = fmaf(w4[0][k].x, hv.x, a0); a0 = fmaf(w4[0][k].y, hv.y, a0);
      a0 = fmaf(w4[0][k].z, hv.z, a0); a0 = fmaf(w4[0][k].w, hv.w, a0);
      a1 = fmaf(w4[1][k].x, hv.x, a1); a1 = fmaf(w4[1][k].y, hv.y, a1);
      a1 = fmaf(w4[1][k].z, hv.z, a1); a1 = fmaf(w4[1][k].w, hv.w, a1);
      a2 = fmaf(w4[2][k].x, hv.x, a2); a2 = fmaf(w4[2][k].y, hv.y, a2);
      a2 = fmaf(w4[2][k].z, hv.z, a2); a2 = fmaf(w4[2][k].w, hv.w, a2);
      a3 = fmaf(w4[3][k].x, hv.x, a3); a3 = fmaf(w4[3][k].y, hv.y, a3);
      a3 = fmaf(w4[3][k].z, hv.z, a3); a3 = fmaf(w4[3][k].w, hv.w, a3);
    }
    *(float4*)&part[q][j][0] = make_float4(a0, a1, a2, a3);
    __syncthreads();

    if (is_act) {
      const float4 p0 = *(const float4*)&part[0][j][0];
      const float4 p1 = *(const float4*)&part[1][j][0];
      const float4 p2 = *(const float4*)&part[2][j][0];
      const float4 p3 = *(const float4*)&part[3][j][0];
      const float i_g = fsig(p0.x + p1.x + p2.x + p3.x + gxc0);
      const float f_g = fsig(p0.y + p1.y + p2.y + p3.y + gxc1);
      const float g_g = ftanh(p0.z + p1.z + p2.z + p3.z + gxc2);
      const float o_g = fsig(p0.w + p1.w + p2.w + p3.w + gxc3);
      c = f_g * c + i_g * g_g;
      const float h = o_g * ftanh(c);
      h_s[j] = h;
      const size_t idx = ((size_t)t * BB + b) * CC + d * HH + j;
      if (store_bf16) {
        const ushort hi = bf16_rn(h);
        hhi[idx] = hi;
        hlo[idx] = bf16_rn(h - bf16_to_f(hi));
      } else {
        hf32[idx] = h;
      }
    }
    __syncthreads();
    gxc0 = gxn0; gxc1 = gxn1; gxc2 = gxn2; gxc3 = gxn3;
    t += tdir;
  }
}

extern "C" void kernel_launch(void* const* d_in, const int* in_sizes, int n_in,
                              void* d_out, int out_size, void* d_ws, size_t ws_size,
                              hipStream_t stream) {
  const float* x    = (const float*)d_in[0];
  const float* W_ih = (const float*)d_in[1];  // [2][2][512][256]
  const float* W_hh = (const float*)d_in[2];  // [2][2][512][128]
  const float* b_ih = (const float*)d_in[3];  // [2][2][512]
  const float* b_hh = (const float*)d_in[4];
  float* out = (float*)d_out;

  if (ws_size < (size_t)160 * 1024 * 1024) return;

  // A-region (32 MiB) recycled: Xhi/Xlo -> h1hi/h1lo -> h2 fp32
  char* ws = (char*)d_ws;
  ushort* abf_hi = (ushort*)ws;                              // 16 MiB
  ushort* abf_lo = (ushort*)(ws + (size_t)16 * 1024 * 1024); // 16 MiB
  float*  h2     = (float*)ws;                               // 32 MiB (rec1 output)
  float*  gxbuf  = (float*)(ws + (size_t)32 * 1024 * 1024);  // [D][M][512] 128 MiB

  const dim3 tb(32, 8);
  const dim3 tg(TT / 32, CC / 32, BB);
  const dim3 gemm_grid(GG / 64, MM / 128, 2);

  k_transpose_cvt_in<<<tg, tb, 0, stream>>>(x, abf_hi, abf_lo);
  k_gemm_mfma<<<gemm_grid, 256, 0, stream>>>(abf_hi, abf_lo, W_ih, b_ih, b_hh, gxbuf);
  k_lstm_rec<<<64, 512, 0, stream>>>(gxbuf, W_hh, nullptr, abf_hi, abf_lo, 1);
  k_gemm_mfma<<<gemm_grid, 256, 0, stream>>>(abf_hi, abf_lo, W_ih + 2 * GG * CC,
                                             b_ih + 2 * GG, b_hh + 2 * GG, gxbuf);
  k_lstm_rec<<<64, 512, 0, stream>>>(gxbuf, W_hh + 2 * GG * HH, h2, nullptr, nullptr, 0);
  k_transpose_out<<<tg, tb, 0, stream>>>(h2, out);
}